// Round 11
// baseline (24.603 us; speedup 1.0000x reference)
//
#include <hip/hip_runtime.h>

// AtomDistances: out[b,i,j] = mask[b,i]&&mask[b,j]&&(i!=j)
//                  ? 1/(safe_norm(pos[b,nbr[b,i,j]] - pos[b,i]) + 1e-8) : 0
// B=4, A=2048.
//
// R11: j-sliced grid for atomic-free load balance. 4 batches x 32 row-groups
// (64 rows) x 8 j-slices (256 cols) = 1024 blocks x 512 thr, exactly 4
// resident/CU. Per-CU active-row sampling: 256 draws (sigma/mu 6%) vs R8's 32
// (18%) -> makespan 1.5x -> ~1.15x of mean. s is the fastest block index so
// one row-group's 8 slices land on 8 different CUs (correlated load). Lane
// j-span stays 16B contiguous (R7 lesson). Column-mask word hoisted per wave
// (fixed slice). nt stores (R9: plain stores worse). No atomics (R5), no
// prepass (R4). Depth-4 row-rotating prefetch; first 4 rows prefetched
// pre-barrier gated by global mask reads.

typedef float f4 __attribute__((ext_vector_type(4)));
typedef float f2 __attribute__((ext_vector_type(2)));

constexpr int A_DIM = 2048;
constexpr int G     = 32;            // row-groups per batch
constexpr int S     = 8;             // j-slices per batch
constexpr int RPB   = 64;            // rows per block   (A_DIM/G)
constexpr int JW    = 256;           // j-cols per block (A_DIM/S)
constexpr int WPB   = 8;             // waves per block
constexpr int NTHR  = WPB * 64;      // 512

__global__ __launch_bounds__(NTHR, 8) void atom_distances_kernel(
    const float* __restrict__ pos,    // [B, A, 3]
    const int*   __restrict__ nbr,    // [B, A, A]
    const int*   __restrict__ mask,   // [B, A]
    float*       __restrict__ out) {  // [B, A, A]
  __shared__ float    sx[A_DIM];             // 8 KB
  __shared__ f2       syz[A_DIM];            // 16 KB
  __shared__ unsigned smaskbits[A_DIM / 32]; // 256 B

  const int b   = blockIdx.x / (G * S);
  const int rem = blockIdx.x % (G * S);
  const int g   = rem / S;
  const int s   = rem % S;                   // fastest: slices spread over CUs
  const int i0  = g * RPB;
  const int j0  = s * JW;

  const float* posb  = pos  + (size_t)b * A_DIM * 3;
  const int*   maskb = mask + (size_t)b * A_DIM;

  const int w    = threadIdx.x >> 6;
  const int lane = threadIdx.x & 63;
  const int jj   = j0 + lane * 4;            // this lane's 4 j's (16B span)
  const size_t bA = (size_t)b * A_DIM;

  // wave w owns rows i0 + k*8 + w, k=0..7 (k*8+w spans [0,64))
#define ROWI(k)  (i0 + (k) * WPB + w)
#define LDN(k)   (*reinterpret_cast<const int4*>(nbr + (bA + ROWI(k)) * A_DIM + jj))

  // pre-barrier: prefetch first 4 rows, gated by global mask (wave-uniform)
  int4 n0, n1, n2, n3;
  const int a0p = maskb[ROWI(0)], a1p = maskb[ROWI(1)],
            a2p = maskb[ROWI(2)], a3p = maskb[ROWI(3)];
  if (a0p) n0 = LDN(0);
  if (a1p) n1 = LDN(1);
  if (a2p) n2 = LDN(2);
  if (a3p) n3 = LDN(3);

  for (int t = threadIdx.x; t < A_DIM; t += NTHR) {   // 4 rounds
    sx[t] = posb[3 * t + 0];
    f2 yz; yz.x = posb[3 * t + 1]; yz.y = posb[3 * t + 2];
    syz[t] = yz;
  }
  for (int r = 0; r < A_DIM / NTHR; ++r) {            // 4 rounds
    const int t = r * NTHR + threadIdx.x;
    const unsigned long long bal = __ballot(maskb[t] != 0);
    if ((threadIdx.x & 63) == 0) {
      const int wbase = t >> 5;
      smaskbits[wbase]     = (unsigned)bal;
      smaskbits[wbase + 1] = (unsigned)(bal >> 32);
    }
  }
  __syncthreads();

  // column mask for this lane's 4 j's — fixed for all rows (hoisted)
  const unsigned wbits = smaskbits[(j0 >> 5) + (lane >> 3)];
  const int bit = (lane & 7) * 4;
  const bool c0 = (wbits >> (bit + 0)) & 1u;
  const bool c1 = (wbits >> (bit + 1)) & 1u;
  const bool c2 = (wbits >> (bit + 2)) & 1u;
  const bool c3 = (wbits >> (bit + 3)) & 1u;

  // row-active bits for k=4..7 (LDS, wave-uniform)
#define ACT(k) ((smaskbits[ROWI(k) >> 5] >> (ROWI(k) & 31)) & 1u)
  const unsigned a4 = ACT(4), a5 = ACT(5), a6 = ACT(6), a7 = ACT(7);

  const f4 zf4 = {0.f, 0.f, 0.f, 0.f};

#define ELEM(nt_, e_, ce_, dst_) { \
    const bool on_ = (ce_) & (i != jj + e_); \
    const int t_ = on_ ? ((nt_) & (A_DIM - 1)) : 0; \
    const float xx_ = sx[t_]; \
    const f2 yz_ = syz[t_]; \
    const float dx_ = xx_ - pix; \
    const float dy_ = yz_.x - piyz.x; \
    const float dz_ = yz_.y - piyz.y; \
    const float d2_ = dx_ * dx_ + dy_ * dy_ + dz_ * dz_; \
    const float inv_ = fminf(__builtin_amdgcn_rsqf(d2_), 1e8f); \
    dst_ = on_ ? inv_ : 0.0f; }

#define ROW(k, act_, n_) { \
    const int i = ROWI(k); \
    f4* op = reinterpret_cast<f4*>(out + (bA + i) * A_DIM + jj); \
    if (act_) { \
      const float pix  = sx[i]; \
      const f2    piyz = syz[i]; \
      f4 r_; \
      ELEM(n_.x, 0, c0, r_.x); \
      ELEM(n_.y, 1, c1, r_.y); \
      ELEM(n_.z, 2, c2, r_.z); \
      ELEM(n_.w, 3, c3, r_.w); \
      __builtin_nontemporal_store(r_, op); \
    } else { \
      __builtin_nontemporal_store(zf4, op); \
    } }

  // depth-4 rotation: rows k+4 prefetched while processing row k
  ROW(0, a0p, n0); if (a4) n0 = LDN(4);
  ROW(1, a1p, n1); if (a5) n1 = LDN(5);
  ROW(2, a2p, n2); if (a6) n2 = LDN(6);
  ROW(3, a3p, n3); if (a7) n3 = LDN(7);
  ROW(4, a4,  n0);
  ROW(5, a5,  n1);
  ROW(6, a6,  n2);
  ROW(7, a7,  n3);

#undef ROW
#undef ELEM
#undef ACT
#undef LDN
#undef ROWI
}

extern "C" void kernel_launch(void* const* d_in, const int* in_sizes, int n_in,
                              void* d_out, int out_size, void* d_ws, size_t ws_size,
                              hipStream_t stream) {
  const float* pos  = (const float*)d_in[0];  // [4,2048,3] f32
  const int*   nbr  = (const int*)d_in[1];    // [4,2048,2048] int32
  const int*   mask = (const int*)d_in[2];    // [4,2048] int32 (bool)
  float*       out  = (float*)d_out;          // [4,2048,2048] f32

  const int B = in_sizes[2] / A_DIM;          // 4
  const int grid = B * G * S;                 // 1024 blocks

  atom_distances_kernel<<<grid, NTHR, 0, stream>>>(pos, nbr, mask, out);
}